// Round 10
// baseline (80.366 us; speedup 1.0000x reference)
//
#include <hip/hip_runtime.h>
#include <hip/hip_bf16.h>

typedef __bf16 v8bf __attribute__((ext_vector_type(8)));
typedef float f32x16 __attribute__((ext_vector_type(16)));
typedef unsigned int uint;
typedef unsigned short ushort;

__device__ inline f32x16 zero16() {
  f32x16 z;
#pragma unroll
  for (int i = 0; i < 16; i++) z[i] = 0.f;
  return z;
}

__device__ inline uint pack_bf16(float a, float b) {
  union { __bf16 h[2]; uint u; } c;
  c.h[0] = (__bf16)a;
  c.h[1] = (__bf16)b;
  return c.u;
}

// ---------------------------------------------------------------------------
// Kernel 0: Wf = [Wq|Wk|Wv]^T as bf16 MFMA B-FRAGMENTS, fragment-major:
// frag_linear = ((t*2 + wn)*3 + nf)*4 + ks   (t = k>>6, 384 frags x 1KB)
// byte = frag_linear*1024 + lane*16, lane = (k>>3 & 1)*32 + (n_within_32)
// (unchanged from R8 — validated)
// ---------------------------------------------------------------------------
__global__ void prep_wt(const float* __restrict__ Wq, const float* __restrict__ Wk,
                        const float* __restrict__ Wv, char* __restrict__ Wf) {
  __shared__ __bf16 tile[64][74];
  const int mat = blockIdx.x >> 4;
  const int kt = blockIdx.x & 15;  // 64-wide k chunk index (t)
  const float* src = (mat == 0) ? Wq : (mat == 1) ? Wk : Wv;
  const int th = threadIdx.x;  // 256 threads
  {
    const int r = th >> 2;          // k-local 0..63
    const int ch = (th & 3) * 16;   // h chunk
    const float4* s4 = (const float4*)(src + (size_t)(kt * 64 + r) * 64 + ch);
#pragma unroll
    for (int j = 0; j < 4; j++) {
      float4 f = s4[j];
      tile[r][ch + 4 * j + 0] = (__bf16)f.x;
      tile[r][ch + 4 * j + 1] = (__bf16)f.y;
      tile[r][ch + 4 * j + 2] = (__bf16)f.z;
      tile[r][ch + 4 * j + 3] = (__bf16)f.w;
    }
  }
  __syncthreads();
  const int h = th >> 2;          // output col n-part, 0..63
  const int cc = (th & 3) * 16;   // k-local chunk of 16
  union { __bf16 o[16]; uint4 u[2]; } pk;
#pragma unroll
  for (int j = 0; j < 16; j++) pk.o[j] = tile[cc + j][h];
  const int n = mat * 64 + h;           // 0..191
  const int wn = (n >= 96) ? 1 : 0;
  const int within = n - wn * 96;
  const int nf = within >> 5;
  const int c = within & 31;
  const int ks = cc >> 4;
  const size_t fb = (size_t)((((kt * 2 + wn) * 3 + nf) * 4) + ks) * 1024;
  *(uint4*)(Wf + fb + c * 16) = pk.u[0];          // hi=0 half (k 0..7 of 16)
  *(uint4*)(Wf + fb + (32 + c) * 16) = pk.u[1];   // hi=1 half (k 8..15)
}

// ---------------------------------------------------------------------------
// Kernel 1: KQV[32768][192] = x * W. 256 blocks x 256 threads = 1024 waves,
// 4 waves/CU, EACH WAVE FULLY INDEPENDENT (no LDS, no barriers, no
// cross-wave waits). Wave owns a 32x192 tile (6 x 32x32 acc frags).
// A: global -> regs, double-buffered one 64-K step ahead. Lane pair
// (l, l+32) covers each row's contiguous 256B per step (full-line use).
// W: fragment-major Wf, 24 x 1KB coalesced L2/L1 loads per step, issued
// at step top, consumed same step (cvt VALU covers L2 latency).
// Each wave self-paces at the HBM rate; stalls never idle the HBM pipe
// because next-step A loads are always already in the memory system.
// ---------------------------------------------------------------------------
__launch_bounds__(256, 1)
__global__ void proj_kernel(const float* __restrict__ x, const char* __restrict__ Wf,
                            __bf16* __restrict__ KQV) {
  const int tid = threadIdx.x;
  const int lane = tid & 63;
  const int wave = tid >> 6;  // 0..3
  const int band = blockIdx.x * 4 + wave;
  const int row0 = band * 32;
  const int hi = lane >> 5;
  // lane's A source: row = row0 + (lane&31), k-base = hi*8 (elements)
  const float4* xp =
      (const float4*)(x + (size_t)(row0 + (lane & 31)) * 1024 + hi * 8);
  const char* wbase = Wf + lane * 16;

  f32x16 acc[6];  // c6 = wn*3 + nf
#pragma unroll
  for (int i = 0; i < 6; i++) acc[i] = zero16();

  float4 a0[8], a1[8];  // A dbuf: [ks*2 + p], p = float4 within the 8-k frag
  v8bf wf[24];          // this step's W fragments [c6*4 + ks]

#define LOADA(buf, T)                                                             \
  {                                                                               \
    _Pragma("unroll") for (int ks = 0; ks < 4; ks++) {                            \
      buf[ks * 2] = xp[(T) * 16 + ks * 4];                                        \
      buf[ks * 2 + 1] = xp[(T) * 16 + ks * 4 + 1];                                \
    }                                                                             \
  }

#define LOADW(T)                                                                  \
  {                                                                               \
    _Pragma("unroll") for (int c6 = 0; c6 < 6; c6++) {                            \
      _Pragma("unroll") for (int ks = 0; ks < 4; ks++) {                          \
        wf[c6 * 4 + ks] = *(const v8bf*)(wbase + (size_t)(T) * 24576 +            \
                                         (c6 / 3) * 12288 + (c6 % 3) * 4096 +     \
                                         ks * 1024);                              \
      }                                                                           \
    }                                                                             \
  }

#define DOMMA(buf)                                                                \
  {                                                                               \
    _Pragma("unroll") for (int ks = 0; ks < 4; ks++) {                            \
      union { __bf16 h[8]; v8bf v; } av;                                          \
      float4 f0 = buf[ks * 2], f1 = buf[ks * 2 + 1];                              \
      av.h[0] = (__bf16)f0.x; av.h[1] = (__bf16)f0.y;                             \
      av.h[2] = (__bf16)f0.z; av.h[3] = (__bf16)f0.w;                             \
      av.h[4] = (__bf16)f1.x; av.h[5] = (__bf16)f1.y;                             \
      av.h[6] = (__bf16)f1.z; av.h[7] = (__bf16)f1.w;                             \
      _Pragma("unroll") for (int c6 = 0; c6 < 6; c6++)                            \
        acc[c6] = __builtin_amdgcn_mfma_f32_32x32x16_bf16(av.v, wf[c6 * 4 + ks],  \
                                                          acc[c6], 0, 0, 0);      \
    }                                                                             \
  }

  // STEP T: W(T) issued first, A(T+1) second (in-order vmcnt: waiting for
  // A(T+1) at step T+1's cvt drains W(T), which is already consumed).
#define STEP(T, CUR, NXT)                                                         \
  LOADW(T);                                                                       \
  LOADA(NXT, (T) + 1);                                                            \
  DOMMA(CUR);

  LOADA(a0, 0);
  STEP(0, a0, a1)
  STEP(1, a1, a0)
  STEP(2, a0, a1)
  STEP(3, a1, a0)
  STEP(4, a0, a1)
  STEP(5, a1, a0)
  STEP(6, a0, a1)
  STEP(7, a1, a0)
  STEP(8, a0, a1)
  STEP(9, a1, a0)
  STEP(10, a0, a1)
  STEP(11, a1, a0)
  STEP(12, a0, a1)
  STEP(13, a1, a0)
  STEP(14, a0, a1)
  // T=15: no next A
  LOADW(15);
  DOMMA(a1);

  // epilogue: write bf16 KQV
#pragma unroll
  for (int c6 = 0; c6 < 6; c6++) {
#pragma unroll
    for (int r = 0; r < 16; r++) {
      int row = row0 + (r & 3) + ((r >> 2) << 3) + ((lane >> 5) << 2);
      int col = (c6 / 3) * 96 + (c6 % 3) * 32 + (lane & 31);
      KQV[(size_t)row * 192 + col] = (__bf16)acc[c6][r];
    }
  }
#undef STEP
#undef LOADA
#undef LOADW
#undef DOMMA
}

// ---------------------------------------------------------------------------
// Kernel 2: causal attention per batch. 256 blocks (= 128 batches x 2 halves)
// x 256 threads (4 waves). Wave owns 32 q-rows. Swapped QK^T -> lane-local
// softmax. (unchanged from R5 — validated)
// ---------------------------------------------------------------------------
__launch_bounds__(256, 1)
__global__ void attn_kernel(const __bf16* __restrict__ KQV, float* __restrict__ out) {
  __shared__ uint4 lds4[81920 / 16];  // K:[256][64] 32KB | Vt:[64][256] 32KB | Q:[128][64] 16KB
  char* Klds = (char*)lds4;
  char* Vlds = (char*)lds4 + 32768;
  char* Qlds = (char*)lds4 + 65536;

  const int tid = threadIdx.x;
  const int lane = tid & 63;
  const int wave = tid >> 6;  // 0..3
  const int b = blockIdx.x >> 1;
  const int half = blockIdx.x & 1;
  const int bt0 = half * 128;
  const size_t base = (size_t)b * 256 * 192;

  {
    int s = tid;
    const uint4* src = (const uint4*)(KQV + base + (size_t)s * 192 + 64);
#pragma unroll
    for (int i = 0; i < 8; i++) {
      uint4 v = src[i];
      int byte = s * 128 + ((i * 16) ^ ((s & 7) << 4));
      *(uint4*)(Klds + byte) = v;
    }
  }
  {
    int s = tid;
    const uint4* src = (const uint4*)(KQV + base + (size_t)s * 192 + 128);
#pragma unroll
    for (int i = 0; i < 8; i++) {
      uint4 v = src[i];
      const ushort* e = (const ushort*)&v;
#pragma unroll
      for (int j = 0; j < 8; j++) {
        int h = i * 8 + j;
        int byte = h * 512 + ((s * 2) ^ ((h & 7) << 4));
        *(ushort*)(Vlds + byte) = e[j];
      }
    }
  }
#pragma unroll
  for (int i = 0; i < 4; i++) {
    int c = tid + i * 256;
    int r = c >> 3, cc = c & 7;
    uint4 v = *(const uint4*)(KQV + base + (size_t)(bt0 + r) * 192 + cc * 8);
    int byte = r * 128 + ((cc * 16) ^ ((r & 7) << 4));
    *(uint4*)(Qlds + byte) = v;
  }
  __syncthreads();

  const int t0 = bt0 + wave * 32;
  const int tg = t0 + (lane & 31);
  const int nf = (t0 >> 5) + 1;

  f32x16 sacc[8];
#pragma unroll
  for (int sf = 0; sf < 8; sf++) {
    f32x16 sv = zero16();
    if (sf < nf) {
#pragma unroll
      for (int ks = 0; ks < 4; ks++) {
        int kbyte = ks * 32 + ((lane >> 5) << 4);
        int krow = sf * 32 + (lane & 31);
        v8bf a = *(const v8bf*)(Klds + krow * 128 + (kbyte ^ ((krow & 7) << 4)));
        int qrow = wave * 32 + (lane & 31);
        v8bf bq = *(const v8bf*)(Qlds + qrow * 128 + (kbyte ^ ((qrow & 7) << 4)));
        sv = __builtin_amdgcn_mfma_f32_32x32x16_bf16(a, bq, sv, 0, 0, 0);
      }
    }
    sacc[sf] = sv;
  }

  float m = -1e30f;
#pragma unroll
  for (int sf = 0; sf < 8; sf++) {
    if (sf < nf) {
#pragma unroll
      for (int r = 0; r < 16; r++) {
        int sg = sf * 32 + (r & 3) + ((r >> 2) << 3) + ((lane >> 5) << 2);
        float v = sacc[sf][r] * 0.125f;
        v = (sg > tg) ? -1e30f : v;
        sacc[sf][r] = v;
        m = fmaxf(m, v);
      }
    }
  }
  m = fmaxf(m, __shfl_xor(m, 32, 64));
  float l = 0.f;
#pragma unroll
  for (int sf = 0; sf < 8; sf++) {
    if (sf < nf) {
#pragma unroll
      for (int r = 0; r < 16; r++) {
        float p = __expf(sacc[sf][r] - m);
        sacc[sf][r] = p;
        l += p;
      }
    }
  }
  l += __shfl_xor(l, 32, 64);
  float inv = 1.0f / l;

  f32x16 oacc[2];
  oacc[0] = zero16();
  oacc[1] = zero16();
  const bool hiLane = (lane >= 32);
#pragma unroll
  for (int sf = 0; sf < 8; sf++) {
    if (sf < nf) {
      uint w[8], ow[8];
#pragma unroll
      for (int q = 0; q < 4; q++) {
        w[2 * q]     = pack_bf16(sacc[sf][4 * q] * inv,     sacc[sf][4 * q + 1] * inv);
        w[2 * q + 1] = pack_bf16(sacc[sf][4 * q + 2] * inv, sacc[sf][4 * q + 3] * inv);
      }
#pragma unroll
      for (int i = 0; i < 8; i++) ow[i] = (uint)__shfl_xor((int)w[i], 32, 64);
#pragma unroll
      for (int ks = 0; ks < 2; ks++) {
        int bse = 4 * ks;
        union { uint u[4]; v8bf v; } A;
        A.u[0] = hiLane ? ow[bse + 2] : w[bse + 0];
        A.u[1] = hiLane ? ow[bse + 3] : w[bse + 1];
        A.u[2] = hiLane ? w[bse + 2] : ow[bse + 0];
        A.u[3] = hiLane ? w[bse + 3] : ow[bse + 1];
        int sbyte0 = (sf * 32 + ks * 16) * 2 + ((lane >> 5) << 4);
#pragma unroll
        for (int hf = 0; hf < 2; hf++) {
          int vrow = hf * 32 + (lane & 31);
          v8bf bv = *(const v8bf*)(Vlds + vrow * 512 + (sbyte0 ^ ((vrow & 7) << 4)));
          oacc[hf] = __builtin_amdgcn_mfma_f32_32x32x16_bf16(A.v, bv, oacc[hf], 0, 0, 0);
        }
      }
    }
  }

#pragma unroll
  for (int hf = 0; hf < 2; hf++) {
#pragma unroll
    for (int r = 0; r < 16; r++) {
      int t = t0 + (r & 3) + ((r >> 2) << 3) + ((lane >> 5) << 2);
      int h = hf * 32 + (lane & 31);
      out[((size_t)b * 256 + t) * 64 + h] = oacc[hf][r];
    }
  }
}

// ---------------------------------------------------------------------------
extern "C" void kernel_launch(void* const* d_in, const int* in_sizes, int n_in,
                              void* d_out, int out_size, void* d_ws, size_t ws_size,
                              hipStream_t stream) {
  const float* x  = (const float*)d_in[0];
  const float* Wk = (const float*)d_in[1];
  const float* Wq = (const float*)d_in[2];
  const float* Wv = (const float*)d_in[3];
  float* out = (float*)d_out;

  // workspace: KQV bf16 [32768][192] (12.58 MB), then fragment-major Wf (384 KB)
  __bf16* KQV = (__bf16*)d_ws;
  char* Wf = (char*)d_ws + (size_t)32768 * 192 * 2;

  prep_wt<<<48, 256, 0, stream>>>(Wq, Wk, Wv, Wf);
  proj_kernel<<<256, 256, 0, stream>>>(x, Wf, KQV);
  attn_kernel<<<256, 256, 0, stream>>>(KQV, out);
}

// Round 11
// 51.462 us; speedup vs baseline: 1.5617x; 1.5617x over previous
//
#include <hip/hip_runtime.h>
#include <hip/hip_bf16.h>

typedef __bf16 v8bf __attribute__((ext_vector_type(8)));
typedef float f32x16 __attribute__((ext_vector_type(16)));
typedef unsigned int uint;
typedef unsigned short ushort;

#define GLOAD16(gsrc, ldst)                                                       \
  __builtin_amdgcn_global_load_lds(                                               \
      (const __attribute__((address_space(1))) unsigned int*)(gsrc),              \
      (__attribute__((address_space(3))) unsigned int*)(ldst), 16, 0, 0)

__device__ inline f32x16 zero16() {
  f32x16 z;
#pragma unroll
  for (int i = 0; i < 16; i++) z[i] = 0.f;
  return z;
}

__device__ inline uint pack_bf16(float a, float b) {
  union { __bf16 h[2]; uint u; } c;
  c.h[0] = (__bf16)a;
  c.h[1] = (__bf16)b;
  return c.u;
}

// ---------------------------------------------------------------------------
// Kernel 0: Wt_s = transpose of [Wq|Wk|Wv] -> bf16, PRE-SWIZZLED:
// element (n,k) at byte n*2048 + (k>>6)*128 + (((k&63)*2) ^ ((n&7)<<4)).
// (R5/R7 version — validated)
// ---------------------------------------------------------------------------
__global__ void prep_wt(const float* __restrict__ Wq, const float* __restrict__ Wk,
                        const float* __restrict__ Wv, char* __restrict__ Wt_s) {
  __shared__ __bf16 tile[64][74];
  const int mat = blockIdx.x >> 4;
  const int c0 = (blockIdx.x & 15) * 64;
  const float* src = (mat == 0) ? Wq : (mat == 1) ? Wk : Wv;
  const int t = threadIdx.x;  // 256 threads
  {
    const int r = t >> 2;
    const int ch = (t & 3) * 16;
    const float4* s4 = (const float4*)(src + (size_t)(c0 + r) * 64 + ch);
#pragma unroll
    for (int j = 0; j < 4; j++) {
      float4 f = s4[j];
      tile[r][ch + 4 * j + 0] = (__bf16)f.x;
      tile[r][ch + 4 * j + 1] = (__bf16)f.y;
      tile[r][ch + 4 * j + 2] = (__bf16)f.z;
      tile[r][ch + 4 * j + 3] = (__bf16)f.w;
    }
  }
  __syncthreads();
  const int h = t >> 2;
  const int cc = (t & 3) * 16;
  union { __bf16 o[16]; uint4 u[2]; } pk;
#pragma unroll
  for (int j = 0; j < 16; j++) pk.o[j] = tile[cc + j][h];
  const int n = mat * 64 + h;
  char* base = Wt_s + (size_t)n * 2048 + (c0 >> 6) * 128;
  const int bc = cc * 2;
  *(uint4*)(base + ((bc) ^ ((n & 7) << 4))) = pk.u[0];
  *(uint4*)(base + ((bc + 16) ^ ((n & 7) << 4))) = pk.u[1];
}

// ---------------------------------------------------------------------------
// Kernel 1: KQV[32768][192] = x * W. 1024 blocks x 128 threads (2 waves),
// 4 INDEPENDENT blocks/CU (LDS 32 KB each). Block tile 32x192; wave tile
// 32x96 (wn = wave); BK=64.
// A: coalesced float4 -> regs (2-deep ping-pong) -> bf16 -> swizzled LDS dbuf.
// W: SINGLE-buffered LDS via global_load_lds from pre-swizzled Wt_s;
// safe because BAR_A (lgkm-only) drains all W ds_reads before GW overwrite.
// BARW keeps the 4 newest A-loads in flight across the barrier (vmcnt(4)).
// 4 de-synchronized block pipelines per CU cover L3/HBM latency (TLP).
// ---------------------------------------------------------------------------
__launch_bounds__(128, 2)
__global__ void proj_kernel(const float* __restrict__ x, const char* __restrict__ Wt_s,
                            __bf16* __restrict__ KQV) {
  __shared__ char lds[32768];
  char* A0 = lds;            // [32][128B] bf16 swizzled, 4 KB
  char* A1 = lds + 4096;
  char* Wb = lds + 8192;     // [192][128B] bf16 swizzled, 24 KB (single buf)

  const int tid = threadIdx.x;
  const int lane = tid & 63;
  const int wave = tid >> 6;  // 0..1
  const int wn = wave;
  const int row0 = blockIdx.x * 32;

  // A staging: thread owns row sr (0..31), 16 contiguous floats at col sc*16
  const int sr = tid >> 2;
  const int sc = tid & 3;
  const float4* xp = (const float4*)(x + (size_t)(row0 + sr) * 1024 + sc * 16);

  f32x16 acc[3];
#pragma unroll
  for (int i = 0; i < 3; i++) acc[i] = zero16();

  float4 sA[4], sB[4];  // 2-deep A register ping-pong

#define SB_ __builtin_amdgcn_sched_barrier(0)

#define LOADA(rr, T)                                                              \
  {                                                                               \
    _Pragma("unroll") for (int j = 0; j < 4; j++) rr[j] = xp[(T) * 16 + j];       \
  }

  // W tile: 192 rows x 128 B = 1536 chunks of 16B; 128 threads x 12 each.
#define GW(T)                                                                     \
  {                                                                               \
    _Pragma("unroll") for (int j = 0; j < 12; j++) {                              \
      int idx = j * 128 + wave * 64 + lane;                                       \
      GLOAD16(Wt_s + (size_t)(idx >> 3) * 2048 + (T) * 128 + (idx & 7) * 16,      \
              Wb + j * 2048 + wave * 1024);                                       \
    }                                                                             \
  }

#define CVTWRITE(rr, Abuf)                                                        \
  {                                                                               \
    union { __bf16 h[16]; uint4 u[2]; } cv;                                       \
    _Pragma("unroll") for (int j = 0; j < 4; j++) {                               \
      cv.h[4 * j + 0] = (__bf16)rr[j].x;                                          \
      cv.h[4 * j + 1] = (__bf16)rr[j].y;                                          \
      cv.h[4 * j + 2] = (__bf16)rr[j].z;                                          \
      cv.h[4 * j + 3] = (__bf16)rr[j].w;                                          \
    }                                                                             \
    *(uint4*)(Abuf + sr * 128 + ((sc * 32) ^ ((sr & 7) << 4))) = cv.u[0];         \
    *(uint4*)(Abuf + sr * 128 + ((sc * 32 + 16) ^ ((sr & 7) << 4))) = cv.u[1];    \
  }

#define MMA(Abuf)                                                                 \
  {                                                                               \
    _Pragma("unroll") for (int ks = 0; ks < 4; ks++) {                            \
      int arow = lane & 31;                                                       \
      int kb = ks * 32 + ((lane >> 5) << 4);                                      \
      v8bf av = *(const v8bf*)(Abuf + arow * 128 + (kb ^ ((arow & 7) << 4)));     \
      _Pragma("unroll") for (int nf = 0; nf < 3; nf++) {                          \
        int brow = wn * 96 + nf * 32 + (lane & 31);                               \
        v8bf bv = *(const v8bf*)(Wb + brow * 128 + (kb ^ ((brow & 7) << 4)));     \
        acc[nf] = __builtin_amdgcn_mfma_f32_32x32x16_bf16(av, bv, acc[nf], 0, 0, 0); \
      }                                                                           \
    }                                                                             \
  }

#define BAR_A                                                                     \
  do {                                                                            \
    asm volatile("s_waitcnt lgkmcnt(0)" ::: "memory");                            \
    __builtin_amdgcn_s_barrier();                                                 \
    SB_;                                                                          \
  } while (0)
#define BARW4                                                                     \
  do {                                                                            \
    asm volatile("s_waitcnt vmcnt(4) lgkmcnt(0)" ::: "memory");                   \
    __builtin_amdgcn_s_barrier();                                                 \
    SB_;                                                                          \
  } while (0)
#define BARW0                                                                     \
  do {                                                                            \
    asm volatile("s_waitcnt vmcnt(0) lgkmcnt(0)" ::: "memory");                   \
    __builtin_amdgcn_s_barrier();                                                 \
    SB_;                                                                          \
  } while (0)

  // STEP t: MMA(t) -> CVT A(t+1) into other LDS buf -> BAR_A (all W/A reads
  // drained) -> GW(t+1) overwrites W -> LOADA(t+2) -> BARW4 (W landed, A flies)
#define STEP(T, ACUR, ANXT, SCONS, SFILL)                                         \
  MMA(ACUR);                                                                      \
  CVTWRITE(SCONS, ANXT);                                                          \
  BAR_A;                                                                          \
  GW(T + 1);                                                                      \
  SB_;                                                                            \
  LOADA(SFILL, T + 2);                                                            \
  BARW4;

  // prologue: W(0) + A(0) staged, A(1) regs in flight
  GW(0);
  SB_;
  LOADA(sA, 0);
  LOADA(sB, 1);
  SB_;
  CVTWRITE(sA, A0);
  BARW4;  // drains GW(0)+ds_writes; sB's 4 loads stay in flight

  STEP(0, A0, A1, sB, sA)
  STEP(1, A1, A0, sA, sB)
  STEP(2, A0, A1, sB, sA)
  STEP(3, A1, A0, sA, sB)
  STEP(4, A0, A1, sB, sA)
  STEP(5, A1, A0, sA, sB)
  STEP(6, A0, A1, sB, sA)
  STEP(7, A1, A0, sA, sB)
  STEP(8, A0, A1, sB, sA)
  STEP(9, A1, A0, sA, sB)
  STEP(10, A0, A1, sB, sA)
  STEP(11, A1, A0, sA, sB)
  STEP(12, A0, A1, sB, sA)
  STEP(13, A1, A0, sA, sB)
  // t=14: no LOADA(16)
  MMA(A0);
  CVTWRITE(sB, A1);
  BAR_A;
  GW(15);
  BARW0;
  // t=15
  MMA(A1);

  // epilogue: write bf16 KQV
#pragma unroll
  for (int nf = 0; nf < 3; nf++) {
#pragma unroll
    for (int r = 0; r < 16; r++) {
      int row = row0 + (r & 3) + ((r >> 2) << 3) + ((lane >> 5) << 2);
      int col = wn * 96 + nf * 32 + (lane & 31);
      KQV[(size_t)row * 192 + col] = (__bf16)acc[nf][r];
    }
  }
#undef STEP
#undef BAR_A
#undef BARW4
#undef BARW0
#undef LOADA
#undef GW
#undef CVTWRITE
#undef MMA
#undef SB_
}

// ---------------------------------------------------------------------------
// Kernel 2: causal attention per batch. 256 blocks (= 128 batches x 2 halves)
// x 256 threads (4 waves). Wave owns 32 q-rows. Swapped QK^T -> lane-local
// softmax. (unchanged from R5 — validated)
// ---------------------------------------------------------------------------
__launch_bounds__(256, 1)
__global__ void attn_kernel(const __bf16* __restrict__ KQV, float* __restrict__ out) {
  __shared__ uint4 lds4[81920 / 16];  // K:[256][64] 32KB | Vt:[64][256] 32KB | Q:[128][64] 16KB
  char* Klds = (char*)lds4;
  char* Vlds = (char*)lds4 + 32768;
  char* Qlds = (char*)lds4 + 65536;

  const int tid = threadIdx.x;
  const int lane = tid & 63;
  const int wave = tid >> 6;  // 0..3
  const int b = blockIdx.x >> 1;
  const int half = blockIdx.x & 1;
  const int bt0 = half * 128;
  const size_t base = (size_t)b * 256 * 192;

  {
    int s = tid;
    const uint4* src = (const uint4*)(KQV + base + (size_t)s * 192 + 64);
#pragma unroll
    for (int i = 0; i < 8; i++) {
      uint4 v = src[i];
      int byte = s * 128 + ((i * 16) ^ ((s & 7) << 4));
      *(uint4*)(Klds + byte) = v;
    }
  }
  {
    int s = tid;
    const uint4* src = (const uint4*)(KQV + base + (size_t)s * 192 + 128);
#pragma unroll
    for (int i = 0; i < 8; i++) {
      uint4 v = src[i];
      const ushort* e = (const ushort*)&v;
#pragma unroll
      for (int j = 0; j < 8; j++) {
        int h = i * 8 + j;
        int byte = h * 512 + ((s * 2) ^ ((h & 7) << 4));
        *(ushort*)(Vlds + byte) = e[j];
      }
    }
  }
#pragma unroll
  for (int i = 0; i < 4; i++) {
    int c = tid + i * 256;
    int r = c >> 3, cc = c & 7;
    uint4 v = *(const uint4*)(KQV + base + (size_t)(bt0 + r) * 192 + cc * 8);
    int byte = r * 128 + ((cc * 16) ^ ((r & 7) << 4));
    *(uint4*)(Qlds + byte) = v;
  }
  __syncthreads();

  const int t0 = bt0 + wave * 32;
  const int tg = t0 + (lane & 31);
  const int nf = (t0 >> 5) + 1;

  f32x16 sacc[8];
#pragma unroll
  for (int sf = 0; sf < 8; sf++) {
    f32x16 sv = zero16();
    if (sf < nf) {
#pragma unroll
      for (int ks = 0; ks < 4; ks++) {
        int kbyte = ks * 32 + ((lane >> 5) << 4);
        int krow = sf * 32 + (lane & 31);
        v8bf a = *(const v8bf*)(Klds + krow * 128 + (kbyte ^ ((krow & 7) << 4)));
        int qrow = wave * 32 + (lane & 31);
        v8bf bq = *(const v8bf*)(Qlds + qrow * 128 + (kbyte ^ ((qrow & 7) << 4)));
        sv = __builtin_amdgcn_mfma_f32_32x32x16_bf16(a, bq, sv, 0, 0, 0);
      }
    }
    sacc[sf] = sv;
  }

  float m = -1e30f;
#pragma unroll
  for (int sf = 0; sf < 8; sf++) {
    if (sf < nf) {
#pragma unroll
      for (int r = 0; r < 16; r++) {
        int sg = sf * 32 + (r & 3) + ((r >> 2) << 3) + ((lane >> 5) << 2);
        float v = sacc[sf][r] * 0.125f;
        v = (sg > tg) ? -1e30f : v;
        sacc[sf][r] = v;
        m = fmaxf(m, v);
      }
    }
  }
  m = fmaxf(m, __shfl_xor(m, 32, 64));
  float l = 0.f;
#pragma unroll
  for (int sf = 0; sf < 8; sf++) {
    if (sf < nf) {
#pragma unroll
      for (int r = 0; r < 16; r++) {
        float p = __expf(sacc[sf][r] - m);
        sacc[sf][r] = p;
        l += p;
      }
    }
  }
  l += __shfl_xor(l, 32, 64);
  float inv = 1.0f / l;

  f32x16 oacc[2];
  oacc[0] = zero16();
  oacc[1] = zero16();
  const bool hiLane = (lane >= 32);
#pragma unroll
  for (int sf = 0; sf < 8; sf++) {
    if (sf < nf) {
      uint w[8], ow[8];
#pragma unroll
      for (int q = 0; q < 4; q++) {
        w[2 * q]     = pack_bf16(sacc[sf][4 * q] * inv,     sacc[sf][4 * q + 1] * inv);
        w[2 * q + 1] = pack_bf16(sacc[sf][4 * q + 2] * inv, sacc[sf][4 * q + 3] * inv);
      }
#pragma unroll
      for (int i = 0; i < 8; i++) ow[i] = (uint)__shfl_xor((int)w[i], 32, 64);
#pragma unroll
      for (int ks = 0; ks < 2; ks++) {
        int bse = 4 * ks;
        union { uint u[4]; v8bf v; } A;
        A.u[0] = hiLane ? ow[bse + 2] : w[bse + 0];
        A.u[1] = hiLane ? ow[bse + 3] : w[bse + 1];
        A.u[2] = hiLane ? w[bse + 2] : ow[bse + 0];
        A.u[3] = hiLane ? w[bse + 3] : ow[bse + 1];
        int sbyte0 = (sf * 32 + ks * 16) * 2 + ((lane >> 5) << 4);
#pragma unroll
        for (int hf = 0; hf < 2; hf++) {
          int vrow = hf * 32 + (lane & 31);
          v8bf bv = *(const v8bf*)(Vlds + vrow * 512 + (sbyte0 ^ ((vrow & 7) << 4)));
          oacc[hf] = __builtin_amdgcn_mfma_f32_32x32x16_bf16(A.v, bv, oacc[hf], 0, 0, 0);
        }
      }
    }
  }

#pragma unroll
  for (int hf = 0; hf < 2; hf++) {
#pragma unroll
    for (int r = 0; r < 16; r++) {
      int t = t0 + (r & 3) + ((r >> 2) << 3) + ((lane >> 5) << 2);
      int h = hf * 32 + (lane & 31);
      out[((size_t)b * 256 + t) * 64 + h] = oacc[hf][r];
    }
  }
}

// ---------------------------------------------------------------------------
extern "C" void kernel_launch(void* const* d_in, const int* in_sizes, int n_in,
                              void* d_out, int out_size, void* d_ws, size_t ws_size,
                              hipStream_t stream) {
  const float* x  = (const float*)d_in[0];
  const float* Wk = (const float*)d_in[1];
  const float* Wq = (const float*)d_in[2];
  const float* Wv = (const float*)d_in[3];
  float* out = (float*)d_out;

  // workspace: KQV bf16 [32768][192] (12.58 MB), then pre-swizzled Wt (384 KB)
  __bf16* KQV = (__bf16*)d_ws;
  char* Wt_s  = (char*)d_ws + (size_t)32768 * 192 * 2;

  prep_wt<<<48, 256, 0, stream>>>(Wq, Wk, Wv, Wt_s);
  proj_kernel<<<1024, 128, 0, stream>>>(x, Wt_s, KQV);
  attn_kernel<<<256, 256, 0, stream>>>(KQV, out);
}

// Round 12
// 51.457 us; speedup vs baseline: 1.5618x; 1.0001x over previous
//
#include <hip/hip_runtime.h>
#include <hip/hip_bf16.h>

typedef __bf16 v8bf __attribute__((ext_vector_type(8)));
typedef float f32x16 __attribute__((ext_vector_type(16)));
typedef unsigned int uint;
typedef unsigned short ushort;

#define GLOAD16(gsrc, ldst)                                                       \
  __builtin_amdgcn_global_load_lds(                                               \
      (const __attribute__((address_space(1))) unsigned int*)(gsrc),              \
      (__attribute__((address_space(3))) unsigned int*)(ldst), 16, 0, 0)

__device__ inline f32x16 zero16() {
  f32x16 z;
#pragma unroll
  for (int i = 0; i < 16; i++) z[i] = 0.f;
  return z;
}

__device__ inline uint pack_bf16(float a, float b) {
  union { __bf16 h[2]; uint u; } c;
  c.h[0] = (__bf16)a;
  c.h[1] = (__bf16)b;
  return c.u;
}

// ---------------------------------------------------------------------------
// Kernel 0: Wt_s = transpose of [Wq|Wk|Wv] -> bf16, PRE-SWIZZLED:
// element (n,k) at byte n*2048 + (k>>6)*128 + (((k&63)*2) ^ ((n&7)<<4)).
// (R5/R7 version — validated)
// ---------------------------------------------------------------------------
__global__ void prep_wt(const float* __restrict__ Wq, const float* __restrict__ Wk,
                        const float* __restrict__ Wv, char* __restrict__ Wt_s) {
  __shared__ __bf16 tile[64][74];
  const int mat = blockIdx.x >> 4;
  const int c0 = (blockIdx.x & 15) * 64;
  const float* src = (mat == 0) ? Wq : (mat == 1) ? Wk : Wv;
  const int t = threadIdx.x;  // 256 threads
  {
    const int r = t >> 2;
    const int ch = (t & 3) * 16;
    const float4* s4 = (const float4*)(src + (size_t)(c0 + r) * 64 + ch);
#pragma unroll
    for (int j = 0; j < 4; j++) {
      float4 f = s4[j];
      tile[r][ch + 4 * j + 0] = (__bf16)f.x;
      tile[r][ch + 4 * j + 1] = (__bf16)f.y;
      tile[r][ch + 4 * j + 2] = (__bf16)f.z;
      tile[r][ch + 4 * j + 3] = (__bf16)f.w;
    }
  }
  __syncthreads();
  const int h = t >> 2;
  const int cc = (t & 3) * 16;
  union { __bf16 o[16]; uint4 u[2]; } pk;
#pragma unroll
  for (int j = 0; j < 16; j++) pk.o[j] = tile[cc + j][h];
  const int n = mat * 64 + h;
  char* base = Wt_s + (size_t)n * 2048 + (c0 >> 6) * 128;
  const int bc = cc * 2;
  *(uint4*)(base + ((bc) ^ ((n & 7) << 4))) = pk.u[0];
  *(uint4*)(base + ((bc + 16) ^ ((n & 7) << 4))) = pk.u[1];
}

// ---------------------------------------------------------------------------
// Kernel 1: KQV[32768][192] = x * W. 1024 blocks x 128 threads (2 waves),
// 4 INDEPENDENT blocks/CU (LDS 32 KB each). Block tile 32x192; wave tile
// 32x96 (wn = wave); BK=64.
// A: coalesced float4 -> regs (2-deep ping-pong) -> bf16 -> swizzled LDS dbuf.
// W: SINGLE-buffered LDS via global_load_lds from pre-swizzled Wt_s;
// safe because BAR_A (lgkm-only) drains all W ds_reads before GW overwrite.
// BARW keeps the 4 newest A-loads in flight across the barrier (vmcnt(4)).
// 4 de-synchronized block pipelines per CU cover L3/HBM latency (TLP).
// ---------------------------------------------------------------------------
__launch_bounds__(128, 2)
__global__ void proj_kernel(const float* __restrict__ x, const char* __restrict__ Wt_s,
                            __bf16* __restrict__ KQV) {
  __shared__ char lds[32768];
  char* A0 = lds;            // [32][128B] bf16 swizzled, 4 KB
  char* A1 = lds + 4096;
  char* Wb = lds + 8192;     // [192][128B] bf16 swizzled, 24 KB (single buf)

  const int tid = threadIdx.x;
  const int lane = tid & 63;
  const int wave = tid >> 6;  // 0..1
  const int wn = wave;
  const int row0 = blockIdx.x * 32;

  // A staging: thread owns row sr (0..31), 16 contiguous floats at col sc*16
  const int sr = tid >> 2;
  const int sc = tid & 3;
  const float4* xp = (const float4*)(x + (size_t)(row0 + sr) * 1024 + sc * 16);

  f32x16 acc[3];
#pragma unroll
  for (int i = 0; i < 3; i++) acc[i] = zero16();

  float4 sA[4], sB[4];  // 2-deep A register ping-pong

#define SB_ __builtin_amdgcn_sched_barrier(0)

#define LOADA(rr, T)                                                              \
  {                                                                               \
    _Pragma("unroll") for (int j = 0; j < 4; j++) rr[j] = xp[(T) * 16 + j];       \
  }

  // W tile: 192 rows x 128 B = 1536 chunks of 16B; 128 threads x 12 each.
#define GW(T)                                                                     \
  {                                                                               \
    _Pragma("unroll") for (int j = 0; j < 12; j++) {                              \
      int idx = j * 128 + wave * 64 + lane;                                       \
      GLOAD16(Wt_s + (size_t)(idx >> 3) * 2048 + (T) * 128 + (idx & 7) * 16,      \
              Wb + j * 2048 + wave * 1024);                                       \
    }                                                                             \
  }

#define CVTWRITE(rr, Abuf)                                                        \
  {                                                                               \
    union { __bf16 h[16]; uint4 u[2]; } cv;                                       \
    _Pragma("unroll") for (int j = 0; j < 4; j++) {                               \
      cv.h[4 * j + 0] = (__bf16)rr[j].x;                                          \
      cv.h[4 * j + 1] = (__bf16)rr[j].y;                                          \
      cv.h[4 * j + 2] = (__bf16)rr[j].z;                                          \
      cv.h[4 * j + 3] = (__bf16)rr[j].w;                                          \
    }                                                                             \
    *(uint4*)(Abuf + sr * 128 + ((sc * 32) ^ ((sr & 7) << 4))) = cv.u[0];         \
    *(uint4*)(Abuf + sr * 128 + ((sc * 32 + 16) ^ ((sr & 7) << 4))) = cv.u[1];    \
  }

#define MMA(Abuf)                                                                 \
  {                                                                               \
    _Pragma("unroll") for (int ks = 0; ks < 4; ks++) {                            \
      int arow = lane & 31;                                                       \
      int kb = ks * 32 + ((lane >> 5) << 4);                                      \
      v8bf av = *(const v8bf*)(Abuf + arow * 128 + (kb ^ ((arow & 7) << 4)));     \
      _Pragma("unroll") for (int nf = 0; nf < 3; nf++) {                          \
        int brow = wn * 96 + nf * 32 + (lane & 31);                               \
        v8bf bv = *(const v8bf*)(Wb + brow * 128 + (kb ^ ((brow & 7) << 4)));     \
        acc[nf] = __builtin_amdgcn_mfma_f32_32x32x16_bf16(av, bv, acc[nf], 0, 0, 0); \
      }                                                                           \
    }                                                                             \
  }

#define BAR_A                                                                     \
  do {                                                                            \
    asm volatile("s_waitcnt lgkmcnt(0)" ::: "memory");                            \
    __builtin_amdgcn_s_barrier();                                                 \
    SB_;                                                                          \
  } while (0)
#define BARW4                                                                     \
  do {                                                                            \
    asm volatile("s_waitcnt vmcnt(4) lgkmcnt(0)" ::: "memory");                   \
    __builtin_amdgcn_s_barrier();                                                 \
    SB_;                                                                          \
  } while (0)
#define BARW0                                                                     \
  do {                                                                            \
    asm volatile("s_waitcnt vmcnt(0) lgkmcnt(0)" ::: "memory");                   \
    __builtin_amdgcn_s_barrier();                                                 \
    SB_;                                                                          \
  } while (0)

  // STEP t: MMA(t) -> CVT A(t+1) into other LDS buf -> BAR_A (all W/A reads
  // drained) -> GW(t+1) overwrites W -> LOADA(t+2) -> BARW4 (W landed, A flies)
#define STEP(T, ACUR, ANXT, SCONS, SFILL)                                         \
  MMA(ACUR);                                                                      \
  CVTWRITE(SCONS, ANXT);                                                          \
  BAR_A;                                                                          \
  GW(T + 1);                                                                      \
  SB_;                                                                            \
  LOADA(SFILL, T + 2);                                                            \
  BARW4;

  // prologue: W(0) + A(0) staged, A(1) regs in flight
  GW(0);
  SB_;
  LOADA(sA, 0);
  LOADA(sB, 1);
  SB_;
  CVTWRITE(sA, A0);
  BARW4;  // drains GW(0)+ds_writes; sB's 4 loads stay in flight

  STEP(0, A0, A1, sB, sA)
  STEP(1, A1, A0, sA, sB)
  STEP(2, A0, A1, sB, sA)
  STEP(3, A1, A0, sA, sB)
  STEP(4, A0, A1, sB, sA)
  STEP(5, A1, A0, sA, sB)
  STEP(6, A0, A1, sB, sA)
  STEP(7, A1, A0, sA, sB)
  STEP(8, A0, A1, sB, sA)
  STEP(9, A1, A0, sA, sB)
  STEP(10, A0, A1, sB, sA)
  STEP(11, A1, A0, sA, sB)
  STEP(12, A0, A1, sB, sA)
  STEP(13, A1, A0, sA, sB)
  // t=14: no LOADA(16)
  MMA(A0);
  CVTWRITE(sB, A1);
  BAR_A;
  GW(15);
  BARW0;
  // t=15
  MMA(A1);

  // epilogue: write bf16 KQV
#pragma unroll
  for (int nf = 0; nf < 3; nf++) {
#pragma unroll
    for (int r = 0; r < 16; r++) {
      int row = row0 + (r & 3) + ((r >> 2) << 3) + ((lane >> 5) << 2);
      int col = wn * 96 + nf * 32 + (lane & 31);
      KQV[(size_t)row * 192 + col] = (__bf16)acc[nf][r];
    }
  }
#undef STEP
#undef BAR_A
#undef BARW4
#undef BARW0
#undef LOADA
#undef GW
#undef CVTWRITE
#undef MMA
#undef SB_
}

// ---------------------------------------------------------------------------
// Kernel 2: causal attention per batch. 256 blocks (= 128 batches x 2 halves)
// x 256 threads (4 waves). Wave owns 32 q-rows. Swapped QK^T -> lane-local
// softmax. (unchanged from R5 — validated)
// ---------------------------------------------------------------------------
__launch_bounds__(256, 1)
__global__ void attn_kernel(const __bf16* __restrict__ KQV, float* __restrict__ out) {
  __shared__ uint4 lds4[81920 / 16];  // K:[256][64] 32KB | Vt:[64][256] 32KB | Q:[128][64] 16KB
  char* Klds = (char*)lds4;
  char* Vlds = (char*)lds4 + 32768;
  char* Qlds = (char*)lds4 + 65536;

  const int tid = threadIdx.x;
  const int lane = tid & 63;
  const int wave = tid >> 6;  // 0..3
  const int b = blockIdx.x >> 1;
  const int half = blockIdx.x & 1;
  const int bt0 = half * 128;
  const size_t base = (size_t)b * 256 * 192;

  {
    int s = tid;
    const uint4* src = (const uint4*)(KQV + base + (size_t)s * 192 + 64);
#pragma unroll
    for (int i = 0; i < 8; i++) {
      uint4 v = src[i];
      int byte = s * 128 + ((i * 16) ^ ((s & 7) << 4));
      *(uint4*)(Klds + byte) = v;
    }
  }
  {
    int s = tid;
    const uint4* src = (const uint4*)(KQV + base + (size_t)s * 192 + 128);
#pragma unroll
    for (int i = 0; i < 8; i++) {
      uint4 v = src[i];
      const ushort* e = (const ushort*)&v;
#pragma unroll
      for (int j = 0; j < 8; j++) {
        int h = i * 8 + j;
        int byte = h * 512 + ((s * 2) ^ ((h & 7) << 4));
        *(ushort*)(Vlds + byte) = e[j];
      }
    }
  }
#pragma unroll
  for (int i = 0; i < 4; i++) {
    int c = tid + i * 256;
    int r = c >> 3, cc = c & 7;
    uint4 v = *(const uint4*)(KQV + base + (size_t)(bt0 + r) * 192 + cc * 8);
    int byte = r * 128 + ((cc * 16) ^ ((r & 7) << 4));
    *(uint4*)(Qlds + byte) = v;
  }
  __syncthreads();

  const int t0 = bt0 + wave * 32;
  const int tg = t0 + (lane & 31);
  const int nf = (t0 >> 5) + 1;

  f32x16 sacc[8];
#pragma unroll
  for (int sf = 0; sf < 8; sf++) {
    f32x16 sv = zero16();
    if (sf < nf) {
#pragma unroll
      for (int ks = 0; ks < 4; ks++) {
        int kbyte = ks * 32 + ((lane >> 5) << 4);
        int krow = sf * 32 + (lane & 31);
        v8bf a = *(const v8bf*)(Klds + krow * 128 + (kbyte ^ ((krow & 7) << 4)));
        int qrow = wave * 32 + (lane & 31);
        v8bf bq = *(const v8bf*)(Qlds + qrow * 128 + (kbyte ^ ((qrow & 7) << 4)));
        sv = __builtin_amdgcn_mfma_f32_32x32x16_bf16(a, bq, sv, 0, 0, 0);
      }
    }
    sacc[sf] = sv;
  }

  float m = -1e30f;
#pragma unroll
  for (int sf = 0; sf < 8; sf++) {
    if (sf < nf) {
#pragma unroll
      for (int r = 0; r < 16; r++) {
        int sg = sf * 32 + (r & 3) + ((r >> 2) << 3) + ((lane >> 5) << 2);
        float v = sacc[sf][r] * 0.125f;
        v = (sg > tg) ? -1e30f : v;
        sacc[sf][r] = v;
        m = fmaxf(m, v);
      }
    }
  }
  m = fmaxf(m, __shfl_xor(m, 32, 64));
  float l = 0.f;
#pragma unroll
  for (int sf = 0; sf < 8; sf++) {
    if (sf < nf) {
#pragma unroll
      for (int r = 0; r < 16; r++) {
        float p = __expf(sacc[sf][r] - m);
        sacc[sf][r] = p;
        l += p;
      }
    }
  }
  l += __shfl_xor(l, 32, 64);
  float inv = 1.0f / l;

  f32x16 oacc[2];
  oacc[0] = zero16();
  oacc[1] = zero16();
  const bool hiLane = (lane >= 32);
#pragma unroll
  for (int sf = 0; sf < 8; sf++) {
    if (sf < nf) {
      uint w[8], ow[8];
#pragma unroll
      for (int q = 0; q < 4; q++) {
        w[2 * q]     = pack_bf16(sacc[sf][4 * q] * inv,     sacc[sf][4 * q + 1] * inv);
        w[2 * q + 1] = pack_bf16(sacc[sf][4 * q + 2] * inv, sacc[sf][4 * q + 3] * inv);
      }
#pragma unroll
      for (int i = 0; i < 8; i++) ow[i] = (uint)__shfl_xor((int)w[i], 32, 64);
#pragma unroll
      for (int ks = 0; ks < 2; ks++) {
        int bse = 4 * ks;
        union { uint u[4]; v8bf v; } A;
        A.u[0] = hiLane ? ow[bse + 2] : w[bse + 0];
        A.u[1] = hiLane ? ow[bse + 3] : w[bse + 1];
        A.u[2] = hiLane ? w[bse + 2] : ow[bse + 0];
        A.u[3] = hiLane ? w[bse + 3] : ow[bse + 1];
        int sbyte0 = (sf * 32 + ks * 16) * 2 + ((lane >> 5) << 4);
#pragma unroll
        for (int hf = 0; hf < 2; hf++) {
          int vrow = hf * 32 + (lane & 31);
          v8bf bv = *(const v8bf*)(Vlds + vrow * 512 + (sbyte0 ^ ((vrow & 7) << 4)));
          oacc[hf] = __builtin_amdgcn_mfma_f32_32x32x16_bf16(A.v, bv, oacc[hf], 0, 0, 0);
        }
      }
    }
  }

#pragma unroll
  for (int hf = 0; hf < 2; hf++) {
#pragma unroll
    for (int r = 0; r < 16; r++) {
      int t = t0 + (r & 3) + ((r >> 2) << 3) + ((lane >> 5) << 2);
      int h = hf * 32 + (lane & 31);
      out[((size_t)b * 256 + t) * 64 + h] = oacc[hf][r];
    }
  }
}

// ---------------------------------------------------------------------------
extern "C" void kernel_launch(void* const* d_in, const int* in_sizes, int n_in,
                              void* d_out, int out_size, void* d_ws, size_t ws_size,
                              hipStream_t stream) {
  const float* x  = (const float*)d_in[0];
  const float* Wk = (const float*)d_in[1];
  const float* Wq = (const float*)d_in[2];
  const float* Wv = (const float*)d_in[3];
  float* out = (float*)d_out;

  // workspace: KQV bf16 [32768][192] (12.58 MB), then pre-swizzled Wt (384 KB)
  __bf16* KQV = (__bf16*)d_ws;
  char* Wt_s  = (char*)d_ws + (size_t)32768 * 192 * 2;

  prep_wt<<<48, 256, 0, stream>>>(Wq, Wk, Wv, Wt_s);
  proj_kernel<<<1024, 128, 0, stream>>>(x, Wt_s, KQV);
  attn_kernel<<<256, 256, 0, stream>>>(KQV, out);
}

// Round 13
// 47.753 us; speedup vs baseline: 1.6829x; 1.0776x over previous
//
#include <hip/hip_runtime.h>
#include <hip/hip_bf16.h>

typedef __bf16 v8bf __attribute__((ext_vector_type(8)));
typedef float f32x16 __attribute__((ext_vector_type(16)));
typedef unsigned int uint;
typedef unsigned short ushort;

#define GLOAD16(gsrc, ldst)                                                       \
  __builtin_amdgcn_global_load_lds(                                               \
      (const __attribute__((address_space(1))) unsigned int*)(gsrc),              \
      (__attribute__((address_space(3))) unsigned int*)(ldst), 16, 0, 0)

__device__ inline f32x16 zero16() {
  f32x16 z;
#pragma unroll
  for (int i = 0; i < 16; i++) z[i] = 0.f;
  return z;
}

__device__ inline uint pack_bf16(float a, float b) {
  union { __bf16 h[2]; uint u; } c;
  c.h[0] = (__bf16)a;
  c.h[1] = (__bf16)b;
  return c.u;
}

// ---------------------------------------------------------------------------
// Kernel 0: Wt_s = transpose of [Wq|Wk|Wv] -> bf16, PRE-SWIZZLED:
// element (n,k) at byte n*2048 + (k>>6)*128 + (((k&63)*2) ^ ((n&7)<<4)).
// (R5/R7 version — validated, unchanged)
// ---------------------------------------------------------------------------
__global__ void prep_wt(const float* __restrict__ Wq, const float* __restrict__ Wk,
                        const float* __restrict__ Wv, char* __restrict__ Wt_s) {
  __shared__ __bf16 tile[64][74];
  const int mat = blockIdx.x >> 4;
  const int c0 = (blockIdx.x & 15) * 64;
  const float* src = (mat == 0) ? Wq : (mat == 1) ? Wk : Wv;
  const int t = threadIdx.x;  // 256 threads
  {
    const int r = t >> 2;
    const int ch = (t & 3) * 16;
    const float4* s4 = (const float4*)(src + (size_t)(c0 + r) * 64 + ch);
#pragma unroll
    for (int j = 0; j < 4; j++) {
      float4 f = s4[j];
      tile[r][ch + 4 * j + 0] = (__bf16)f.x;
      tile[r][ch + 4 * j + 1] = (__bf16)f.y;
      tile[r][ch + 4 * j + 2] = (__bf16)f.z;
      tile[r][ch + 4 * j + 3] = (__bf16)f.w;
    }
  }
  __syncthreads();
  const int h = t >> 2;
  const int cc = (t & 3) * 16;
  union { __bf16 o[16]; uint4 u[2]; } pk;
#pragma unroll
  for (int j = 0; j < 16; j++) pk.o[j] = tile[cc + j][h];
  const int n = mat * 64 + h;
  char* base = Wt_s + (size_t)n * 2048 + (c0 >> 6) * 128;
  const int bc = cc * 2;
  *(uint4*)(base + ((bc) ^ ((n & 7) << 4))) = pk.u[0];
  *(uint4*)(base + ((bc + 16) ^ ((n & 7) << 4))) = pk.u[1];
}

// ---------------------------------------------------------------------------
// Kernel 1: projections. R7 core EXACTLY (4-deep A reg pipe, W dbuf via
// global_load_lds, counted-vmcnt barriers). Epilogue changed: writes
//   Qa[g][64] row-major bf16, Va[g][64] row-major bf16,
//   Ka = pre-swizzled byte image of attn's K-LDS:
//        byte(b,s,h) = b*32768 + s*128 + ((h*2) ^ ((s&7)<<4))
// so attn can stage K with LINEAR global_load_lds (swizzle baked in).
// ---------------------------------------------------------------------------
__launch_bounds__(256, 2)
__global__ void proj_kernel(const float* __restrict__ x, const char* __restrict__ Wt_s,
                            __bf16* __restrict__ Qa, char* __restrict__ Ka,
                            __bf16* __restrict__ Va) {
  __shared__ char lds[65536];
  char* A0 = lds;            // [64][128B] bf16 swizzled, 8 KB
  char* A1 = lds + 8192;
  char* W0 = lds + 16384;    // [192][128B] bf16 swizzled, 24 KB
  char* W1 = lds + 40960;

  const int tid = threadIdx.x;
  const int lane = tid & 63;
  const int wave = tid >> 6;  // 0..3
  const int wm = wave >> 1;
  const int wn = wave & 1;
  const int row0 = blockIdx.x * 64;

  const int sr = tid >> 2;
  const int sc = tid & 3;
  const float4* xp = (const float4*)(x + (size_t)(row0 + sr) * 1024 + sc * 16);

  f32x16 acc[3];
#pragma unroll
  for (int i = 0; i < 3; i++) acc[i] = zero16();

  float4 s0[4], s1[4], s2[4], s3[4];

#define SB __builtin_amdgcn_sched_barrier(0)

#define LOADA(rr, t)                                                              \
  {                                                                               \
    _Pragma("unroll") for (int j = 0; j < 4; j++) rr[j] = xp[(t) * 16 + j];       \
  }

#define GW(t, Wbuf)                                                               \
  {                                                                               \
    _Pragma("unroll") for (int j = 0; j < 6; j++) {                               \
      int idx = wave * 64 + j * 256 + lane;                                       \
      GLOAD16(Wt_s + (size_t)(idx >> 3) * 2048 + (t) * 128 + (idx & 7) * 16,      \
              Wbuf + wave * 1024 + j * 4096);                                     \
    }                                                                             \
  }

#define CVTWRITE(rr, Abuf)                                                        \
  {                                                                               \
    union { __bf16 h[16]; uint4 u[2]; } cv;                                       \
    _Pragma("unroll") for (int j = 0; j < 4; j++) {                               \
      cv.h[4 * j + 0] = (__bf16)rr[j].x;                                          \
      cv.h[4 * j + 1] = (__bf16)rr[j].y;                                          \
      cv.h[4 * j + 2] = (__bf16)rr[j].z;                                          \
      cv.h[4 * j + 3] = (__bf16)rr[j].w;                                          \
    }                                                                             \
    *(uint4*)(Abuf + sr * 128 + ((sc * 32) ^ ((sr & 7) << 4))) = cv.u[0];         \
    *(uint4*)(Abuf + sr * 128 + ((sc * 32 + 16) ^ ((sr & 7) << 4))) = cv.u[1];    \
  }

#define MMA(Abuf, Wbuf)                                                           \
  {                                                                               \
    _Pragma("unroll") for (int ks = 0; ks < 4; ks++) {                            \
      int arow = wm * 32 + (lane & 31);                                           \
      int kb = ks * 32 + ((lane >> 5) << 4);                                      \
      v8bf av = *(const v8bf*)(Abuf + arow * 128 + (kb ^ ((arow & 7) << 4)));     \
      _Pragma("unroll") for (int nf = 0; nf < 3; nf++) {                          \
        int brow = wn * 96 + nf * 32 + (lane & 31);                               \
        v8bf bv = *(const v8bf*)(Wbuf + brow * 128 + (kb ^ ((brow & 7) << 4)));   \
        acc[nf] = __builtin_amdgcn_mfma_f32_32x32x16_bf16(av, bv, acc[nf], 0, 0, 0); \
      }                                                                           \
    }                                                                             \
  }

#define BAR4                                                                      \
  do {                                                                            \
    asm volatile("s_waitcnt vmcnt(4) lgkmcnt(0)" ::: "memory");                   \
    __builtin_amdgcn_s_barrier();                                                 \
    SB;                                                                           \
  } while (0)
#define BAR0                                                                      \
  do {                                                                            \
    asm volatile("s_waitcnt vmcnt(0) lgkmcnt(0)" ::: "memory");                   \
    __builtin_amdgcn_s_barrier();                                                 \
    SB;                                                                           \
  } while (0)

#define STEP(T, SI, SC_, ACUR, WCUR, ANXT, WNXT)                                  \
  GW(T + 1, WNXT);                                                                \
  SB;                                                                             \
  LOADA(SI, T + 2);                                                               \
  SB;                                                                             \
  MMA(ACUR, WCUR);                                                                \
  CVTWRITE(SC_, ANXT);                                                            \
  BAR4;

  GW(0, W0);
  SB;
  LOADA(s0, 0);
  LOADA(s1, 1);
  SB;
  CVTWRITE(s0, A0);
  BAR4;

  STEP(0, s2, s1, A0, W0, A1, W1)
  STEP(1, s3, s2, A1, W1, A0, W0)
  STEP(2, s0, s3, A0, W0, A1, W1)
  STEP(3, s1, s0, A1, W1, A0, W0)
  STEP(4, s2, s1, A0, W0, A1, W1)
  STEP(5, s3, s2, A1, W1, A0, W0)
  STEP(6, s0, s3, A0, W0, A1, W1)
  STEP(7, s1, s0, A1, W1, A0, W0)
  STEP(8, s2, s1, A0, W0, A1, W1)
  STEP(9, s3, s2, A1, W1, A0, W0)
  STEP(10, s0, s3, A0, W0, A1, W1)
  STEP(11, s1, s0, A1, W1, A0, W0)
  STEP(12, s2, s1, A0, W0, A1, W1)
  STEP(13, s3, s2, A1, W1, A0, W0)
  GW(15, W1);
  SB;
  MMA(A0, W0);
  CVTWRITE(s3, A1);
  BAR0;
  MMA(A1, W1);

  // epilogue: split into Qa / Ka(pre-swizzled image) / Va
#pragma unroll
  for (int nf = 0; nf < 3; nf++) {
    const int colb = wn * 96 + nf * 32;  // wave-uniform
#pragma unroll
    for (int r = 0; r < 16; r++) {
      int g = row0 + wm * 32 + (r & 3) + ((r >> 2) << 3) + ((lane >> 5) << 2);
      __bf16 val = (__bf16)acc[nf][r];
      if (colb < 64) {                       // Q part, h = colb + lane&31
        Qa[(size_t)g * 64 + colb + (lane & 31)] = val;
      } else if (colb < 128) {               // K part
        int h = colb - 64 + (lane & 31);
        int s = g & 255, bb = g >> 8;
        int byte = s * 128 + ((h * 2) ^ ((s & 7) << 4));
        *(__bf16*)(Ka + (size_t)bb * 32768 + byte) = val;
      } else {                               // V part
        Va[(size_t)g * 64 + colb - 128 + (lane & 31)] = val;
      }
    }
  }
#undef STEP
#undef BAR4
#undef BAR0
#undef LOADA
#undef GW
#undef CVTWRITE
#undef MMA
#undef SB
}

// ---------------------------------------------------------------------------
// Kernel 2: causal attention. 256 blocks (128 batches x 2 halves) x 256 thr.
// Changes vs R5: K staged via 8 LINEAR global_load_lds from the pre-swizzled
// Ka image (zero VALU); Q loaded DIRECT to registers (Q-LDS deleted, 64 KB
// LDS total). V scatter staging + S/softmax/PV/out unchanged (validated).
// ---------------------------------------------------------------------------
__launch_bounds__(256)
__global__ void attn_kernel(const __bf16* __restrict__ Qa, const char* __restrict__ Ka,
                            const __bf16* __restrict__ Va, float* __restrict__ out) {
  __shared__ char lds[65536];  // K:[256][64]swz 32KB | Vt:[64][256]swz 32KB
  char* Klds = lds;
  char* Vlds = lds + 32768;

  const int tid = threadIdx.x;
  const int lane = tid & 63;
  const int wave = tid >> 6;  // 0..3
  const int b = blockIdx.x >> 1;
  const int half = blockIdx.x & 1;
  const int bt0 = half * 128;

  // Q fragments direct to regs (B-operand of swapped QK^T)
  v8bf bq[4];
  {
    const __bf16* qsrc = Qa + (size_t)(b * 256 + bt0 + wave * 32 + (lane & 31)) * 64 +
                         ((lane >> 5) << 3);
#pragma unroll
    for (int ks = 0; ks < 4; ks++) bq[ks] = *(const v8bf*)(qsrc + ks * 16);
  }

  // K staging: linear copy of the pre-swizzled 32 KB image
  {
    const char* ksrc = Ka + (size_t)b * 32768 + wave * 1024 + lane * 16;
#pragma unroll
    for (int i = 0; i < 8; i++)
      GLOAD16(ksrc + i * 4096, Klds + wave * 1024 + i * 4096);
  }
  // V staging: transpose-scatter (unchanged math, source = Va rows)
  {
    int s = tid;
    const uint4* src = (const uint4*)(Va + (size_t)(b * 256 + s) * 64);
#pragma unroll
    for (int i = 0; i < 8; i++) {
      uint4 v = src[i];
      const ushort* e = (const ushort*)&v;
#pragma unroll
      for (int j = 0; j < 8; j++) {
        int h = i * 8 + j;
        int byte = h * 512 + ((s * 2) ^ ((h & 7) << 4));
        *(ushort*)(Vlds + byte) = e[j];
      }
    }
  }
  __syncthreads();

  const int t0 = bt0 + wave * 32;
  const int tg = t0 + (lane & 31);
  const int nf = (t0 >> 5) + 1;

  f32x16 sacc[8];
#pragma unroll
  for (int sf = 0; sf < 8; sf++) {
    f32x16 sv = zero16();
    if (sf < nf) {
#pragma unroll
      for (int ks = 0; ks < 4; ks++) {
        int kbyte = ks * 32 + ((lane >> 5) << 4);
        int krow = sf * 32 + (lane & 31);
        v8bf a = *(const v8bf*)(Klds + krow * 128 + (kbyte ^ ((krow & 7) << 4)));
        sv = __builtin_amdgcn_mfma_f32_32x32x16_bf16(a, bq[ks], sv, 0, 0, 0);
      }
    }
    sacc[sf] = sv;
  }

  float m = -1e30f;
#pragma unroll
  for (int sf = 0; sf < 8; sf++) {
    if (sf < nf) {
#pragma unroll
      for (int r = 0; r < 16; r++) {
        int sg = sf * 32 + (r & 3) + ((r >> 2) << 3) + ((lane >> 5) << 2);
        float v = sacc[sf][r] * 0.125f;
        v = (sg > tg) ? -1e30f : v;
        sacc[sf][r] = v;
        m = fmaxf(m, v);
      }
    }
  }
  m = fmaxf(m, __shfl_xor(m, 32, 64));
  float l = 0.f;
#pragma unroll
  for (int sf = 0; sf < 8; sf++) {
    if (sf < nf) {
#pragma unroll
      for (int r = 0; r < 16; r++) {
        float p = __expf(sacc[sf][r] - m);
        sacc[sf][r] = p;
        l += p;
      }
    }
  }
  l += __shfl_xor(l, 32, 64);
  float inv = 1.0f / l;

  f32x16 oacc[2];
  oacc[0] = zero16();
  oacc[1] = zero16();
  const bool hiLane = (lane >= 32);
#pragma unroll
  for (int sf = 0; sf < 8; sf++) {
    if (sf < nf) {
      uint w[8], ow[8];
#pragma unroll
      for (int q = 0; q < 4; q++) {
        w[2 * q]     = pack_bf16(sacc[sf][4 * q] * inv,     sacc[sf][4 * q + 1] * inv);
        w[2 * q + 1] = pack_bf16(sacc[sf][4 * q + 2] * inv, sacc[sf][4 * q + 3] * inv);
      }
#pragma unroll
      for (int i = 0; i < 8; i++) ow[i] = (uint)__shfl_xor((int)w[i], 32, 64);
#pragma unroll
      for (int ks = 0; ks < 2; ks++) {
        int bse = 4 * ks;
        union { uint u[4]; v8bf v; } A;
        A.u[0] = hiLane ? ow[bse + 2] : w[bse + 0];
        A.u[1] = hiLane ? ow[bse + 3] : w[bse + 1];
        A.u[2] = hiLane ? w[bse + 2] : ow[bse + 0];
        A.u[3] = hiLane ? w[bse + 3] : ow[bse + 1];
        int sbyte0 = (sf * 32 + ks * 16) * 2 + ((lane >> 5) << 4);
#pragma unroll
        for (int hf = 0; hf < 2; hf++) {
          int vrow = hf * 32 + (lane & 31);
          v8bf bv = *(const v8bf*)(Vlds + vrow * 512 + (sbyte0 ^ ((vrow & 7) << 4)));
          oacc[hf] = __builtin_amdgcn_mfma_f32_32x32x16_bf16(A.v, bv, oacc[hf], 0, 0, 0);
        }
      }
    }
  }

#pragma unroll
  for (int hf = 0; hf < 2; hf++) {
#pragma unroll
    for (int r = 0; r < 16; r++) {
      int t = t0 + (r & 3) + ((r >> 2) << 3) + ((lane >> 5) << 2);
      int h = hf * 32 + (lane & 31);
      out[((size_t)b * 256 + t) * 64 + h] = oacc[hf][r];
    }
  }
}

// ---------------------------------------------------------------------------
extern "C" void kernel_launch(void* const* d_in, const int* in_sizes, int n_in,
                              void* d_out, int out_size, void* d_ws, size_t ws_size,
                              hipStream_t stream) {
  const float* x  = (const float*)d_in[0];
  const float* Wk = (const float*)d_in[1];
  const float* Wq = (const float*)d_in[2];
  const float* Wv = (const float*)d_in[3];
  float* out = (float*)d_out;

  // workspace: Qa 4.19MB | Ka 4.19MB | Va 4.19MB | Wt_s 384KB  (= old total)
  __bf16* Qa = (__bf16*)d_ws;
  char* Ka   = (char*)d_ws + 4194304;
  __bf16* Va = (__bf16*)((char*)d_ws + 8388608);
  char* Wt_s = (char*)d_ws + 12582912;

  prep_wt<<<48, 256, 0, stream>>>(Wq, Wk, Wv, Wt_s);
  proj_kernel<<<512, 256, 0, stream>>>(x, Wt_s, Qa, Ka, Va);
  attn_kernel<<<256, 256, 0, stream>>>(Qa, Ka, Va, out);
}